// Round 17
// baseline (27.392 us; speedup 1.0000x reference)
//
#include <hip/hip_runtime.h>

// CfdInterpolateMeshToGrid: B=8, M=8192 mesh pts/batch, G=2048 grid pts/batch,
// D=2, C=64, K=3.  out[g,c] = sum_k w_k * x[nn_k(g), c] / sum_k w_k,
// w_k = 1 / max(d2_k, 1e-16), d2 = (g2 + m2) - 2*dot.
//
// NUMERICS (locked by rounds 1-5 — DO NOT CHANGE):
//   #pragma clang fp contract(off), plus exactly:
//     m2  = (mx*mx) + (my*my)           // unfused
//     g2  = (gx*gx) + (gy*gy)           // unfused
//     p0  = gx*mx; dot = fmaf(gy,my,p0) // fma-ascending k-contraction (BLAS)
//     t   = g2 + m2
//     d2  = fmaf(-2, dot, t)            // == t - (2*dot) bit-exactly
//   Selection = 3 lex-smallest (d2, idx) — identical to stable top_k and
//   visit-order independent (safe with nondeterministic scatter order).
//
// SCHEDULE (round 17): r11-vs-r12 proved launch gaps are ~0.1us in graph
// replay -> splitting is free. r16's single search kernel was capped at
// 2048 waves (8/CU) because selection needs 8 lanes/point, while the gather
// phase (24 scattered 256B x-rows/wave — the latency-heaviest part) has
// 16384 waves of intrinsic parallelism. Split:
//   knn_select: r16 scan+merge+containment+fallback, leaders write
//               (d2 x3, idx x3) SoA -> 512 blocks;
//   knn_gather: WAVE PER POINT (4096 blocks = 32 waves/CU, max occupancy):
//               3 independent row loads + locked epilogue + coalesced store.
// bin_all unchanged (fused ~= split, measured r11/r12).

#define BLK 256
#define LPG 8            // lanes per grid point (select)
#define PPB 32           // grid points per select block (BLK/LPG)
#define NTB 1024
#define NB 32
#define NBINS (NB * NB)
#define PADIDX 0x7FFFFFFF
#define MARGIN 1e-4f

// One block per batch: zero + histogram + scan + LDS-staged scatter +
// coalesced write-out of packed candidates (x, y, m2, idx_bits).
__global__ void bin_all(const float* __restrict__ mesh_pos,
                        int* __restrict__ starts,    // [B][NBINS+1]
                        float4* __restrict__ sxyi,
                        int M)
{
#pragma clang fp contract(off)
    __shared__ int h[NBINS];          // histogram, then cursor
    __shared__ int wsum[16];
    __shared__ int woff[17];
    extern __shared__ char dsm[];     // M*12 bytes: staged sorted array
    float2* stage = (float2*)dsm;
    int*    sidl  = (int*)(dsm + (size_t)M * sizeof(float2));

    const int b = blockIdx.x, t = threadIdx.x;

    h[t] = 0;                         // NBINS == NTB == 1024
    __syncthreads();

    const float2* mp = (const float2*)mesh_pos + (size_t)b * M;
    for (int n = t; n < M; n += NTB) {
        const float2 p = mp[n];
        const int bx = max(0, min((int)(p.x * (float)NB), NB - 1));
        const int by = max(0, min((int)(p.y * (float)NB), NB - 1));
        atomicAdd(&h[by * NB + bx], 1);
    }
    __syncthreads();

    const int v = h[t];
    int sc = v;                       // wave-inclusive scan
    #pragma unroll
    for (int off = 1; off < 64; off <<= 1) {
        int nv = __shfl_up(sc, off, 64);
        if ((t & 63) >= off) sc += nv;
    }
    if ((t & 63) == 63) wsum[t >> 6] = sc;
    __syncthreads();
    if (t == 0) {
        int acc = 0;
        #pragma unroll
        for (int i = 0; i < 16; ++i) { woff[i] = acc; acc += wsum[i]; }
        woff[16] = acc;
    }
    __syncthreads();
    const int excl = woff[t >> 6] + sc - v;
    starts[b * (NBINS + 1) + t] = excl;
    if (t == 0) starts[b * (NBINS + 1) + NBINS] = woff[16];   // = M
    __syncthreads();                  // everyone done reading h[t]
    h[t] = excl;                      // cursor
    __syncthreads();

    for (int n = t; n < M; n += NTB) {
        const float2 p = mp[n];       // L1 hit (just streamed)
        const int bx = max(0, min((int)(p.x * (float)NB), NB - 1));
        const int by = max(0, min((int)(p.y * (float)NB), NB - 1));
        const int pos = atomicAdd(&h[by * NB + bx], 1);
        stage[pos] = p;               // LDS scatter (cheap)
        sidl[pos]  = n;               // batch-local index
    }
    __syncthreads();

    // Coalesced write-out; m2 recomputed with the locked unfused expression.
    for (int n = t; n < M; n += NTB) {
        const float2 p = stage[n];
        const float m2 = (p.x * p.x) + (p.y * p.y);   // unfused (contract off)
        sxyi[(size_t)b * M + n] =
            make_float4(p.x, p.y, m2, __int_as_float(sidl[n]));
    }
}

// lex-(d2, idx) sorted-3 insert; visit-order independent == stable top_k.
#define LEX_INSERT(d2, idx)                                                  \
    if ((d2) < t2 || ((d2) == t2 && (idx) < i2)) {                           \
        if ((d2) < t1 || ((d2) == t1 && (idx) < i1)) {                       \
            t2 = t1; i2 = i1;                                                \
            if ((d2) < t0 || ((d2) == t0 && (idx) < i0)) {                   \
                t1 = t0; i1 = i0; t0 = (d2); i0 = (idx);                     \
            } else { t1 = (d2); i1 = (idx); }                                \
        } else { t2 = (d2); i2 = (idx); }                                    \
    }

#define SCAN_ROW(lo, hi)                                                     \
    for (int sp = (lo) + li; sp < (hi); sp += LPG) {                         \
        const float4 v = bxyi[sp];                                           \
        const float p0  = gx * v.x;                                          \
        const float dot = fmaf(gy, v.y, p0);                                 \
        const float t   = g2 + v.z;                                          \
        const float d2  = fmaf(-2.0f, dot, t);                               \
        const int   idx = __float_as_int(v.w);                               \
        LEX_INSERT(d2, idx)                                                  \
    }

// Select: block = 32 grid points, 8 lanes each; 512 blocks. No LDS/barriers.
// Leaders write (d2 x3, idx x3) to SoA arrays.
__global__ void knn_select(const float* __restrict__ grid_pos,
                           const float4* __restrict__ sxyi,
                           const int* __restrict__ starts,
                           float* __restrict__ dA, float* __restrict__ dB,
                           float* __restrict__ dC,
                           int* __restrict__ jA, int* __restrict__ jB,
                           int* __restrict__ jC,
                           int M, int G)
{
#pragma clang fp contract(off)
    const int tid  = threadIdx.x;
    const int g0   = blockIdx.x * PPB;
    const int b    = g0 / G;              // uniform: PPB divides G
    const int pt   = tid >> 3;            // block-local point 0..31
    const int li   = tid & 7;             // lane within point group
    const int lane = tid & 63;

    const int g = g0 + pt;
    const float2 gp = ((const float2*)grid_pos)[g];   // broadcast in group
    const float gx = gp.x, gy = gp.y;
    const float g2 = (gx * gx) + (gy * gy);           // unfused

    const int gbx = max(0, min((int)(gx * (float)NB), NB - 1));
    const int gby = max(0, min((int)(gy * (float)NB), NB - 1));
    const int bxlo = max(gbx - 1, 0), bxhi = min(gbx + 1, NB - 1);
    const int bylo = max(gby - 1, 0), byhi = min(gby + 1, NB - 1);

    const int* st = starts + b * (NBINS + 1);          // L2-resident (4KB)
    const float4* bxyi = sxyi + (size_t)b * M;

    // Hoist all row bounds: issue the 6 loads before any scanning.
    const int lo0 = st[bylo * NB + bxlo];
    const int hi0 = st[bylo * NB + bxhi + 1];
    int lo1 = 0, hi1 = 0, lo2 = 0, hi2 = 0;
    if (bylo + 1 <= byhi) { lo1 = st[(bylo + 1) * NB + bxlo];
                            hi1 = st[(bylo + 1) * NB + bxhi + 1]; }
    if (bylo + 2 <= byhi) { lo2 = st[(bylo + 2) * NB + bxlo];
                            hi2 = st[(bylo + 2) * NB + bxhi + 1]; }

    float t0 = 1e30f, t1 = 1e30f, t2 = 1e30f;
    int   i0 = PADIDX, i1 = PADIDX, i2 = PADIDX;

    SCAN_ROW(lo0, hi0)
    SCAN_ROW(lo1, hi1)
    SCAN_ROW(lo2, hi2)

    // 8-lane lex extract-pop x3 -> registers (group-uniform after butterfly).
    float wd0, wd1, wd2; int wi0, wi1, wi2;
    #pragma unroll
    for (int r = 0; r < 3; ++r) {
        float rd = t0; int ri = i0;
        #pragma unroll
        for (int off = 1; off < LPG; off <<= 1) {
            float od = __shfl_xor(rd, off, 64);
            int   oi = __shfl_xor(ri, off, 64);
            if (od < rd || (od == rd && oi < ri)) { rd = od; ri = oi; }
        }
        if (r == 0)      { wd0 = rd; wi0 = ri; }
        else if (r == 1) { wd1 = rd; wi1 = ri; }
        else             { wd2 = rd; wi2 = ri; }
        if (t0 == rd && i0 == ri) {
            t0 = t1; i0 = i1; t1 = t2; i1 = i2; t2 = 1e30f; i2 = PADIDX;
        }
    }

    // Containment check (group-uniform): distance to unexamined region.
    const float w = 1.0f / (float)NB;
    const float dl = (bxlo > 0)      ? (gx - (float)bxlo * w)       : 1e30f;
    const float dr = (bxhi < NB - 1) ? ((float)(bxhi + 1) * w - gx) : 1e30f;
    const float dn = (bylo > 0)      ? (gy - (float)bylo * w)       : 1e30f;
    const float dt = (byhi < NB - 1) ? ((float)(byhi + 1) * w - gy) : 1e30f;
    const float bdd = fminf(fminf(dl, dr), fminf(dn, dt));
    const float bd2 = bdd * bdd;
    const bool need = (li == 0) && !(wd2 + MARGIN < bd2);

    // Rare fallback: wave-cooperative exact scan; deliver via registers.
    unsigned long long mask = __ballot(need);
    while (mask) {
        const int l = __builtin_ctzll(mask); mask &= mask - 1;
        const int ptf = ((tid & ~63) + l) >> 3;        // block-local point
        const float2 fgp = ((const float2*)grid_pos)[g0 + ptf];
        const float fgx = fgp.x, fgy = fgp.y;
        const float fg2 = (fgx * fgx) + (fgy * fgy);   // unfused
        float t0 = 1e30f, t1 = 1e30f, t2 = 1e30f;
        int   i0 = PADIDX, i1 = PADIDX, i2 = PADIDX;
        for (int j = lane; j < M; j += 64) {
            const float4 v = bxyi[j];
            const float p0  = fgx * v.x;
            const float dot = fmaf(fgy, v.y, p0);
            const float t   = fg2 + v.z;
            const float d2  = fmaf(-2.0f, dot, t);
            const int   idx = __float_as_int(v.w);
            LEX_INSERT(d2, idx)
        }
        #pragma unroll
        for (int r = 0; r < 3; ++r) {                  // 64-lane butterfly
            float rd = t0; int ri = i0;
            #pragma unroll
            for (int off = 32; off; off >>= 1) {
                float od = __shfl_xor(rd, off, 64);
                int   oi = __shfl_xor(ri, off, 64);
                if (od < rd || (od == rd && oi < ri)) { rd = od; ri = oi; }
            }
            if (pt == ptf) {                           // owning group only
                if (r == 0)      { wd0 = rd; wi0 = ri; }
                else if (r == 1) { wd1 = rd; wi1 = ri; }
                else             { wd2 = rd; wi2 = ri; }
            }
            if (t0 == rd && i0 == ri) {
                t0 = t1; i0 = i1; t1 = t2; i1 = i2; t2 = 1e30f; i2 = PADIDX;
            }
        }
    }

    // Leaders write SoA results (consecutive groups -> consecutive dwords).
    if (li == 0) {
        dA[g] = wd0; dB[g] = wd1; dC[g] = wd2;
        jA[g] = wi0; jB[g] = wi1; jC[g] = wi2;
    }
}

// Gather: one wave per grid point (max TLP: 16384 waves = 32 waves/CU).
// 3 independent 256B row loads + locked epilogue + coalesced store.
__global__ void knn_gather(const float* __restrict__ x,
                           const float* __restrict__ dA,
                           const float* __restrict__ dB,
                           const float* __restrict__ dC,
                           const int* __restrict__ jA,
                           const int* __restrict__ jB,
                           const int* __restrict__ jC,
                           float* __restrict__ out,
                           int M, int G)
{
#pragma clang fp contract(off)
    const int tid  = threadIdx.x;
    const int g    = blockIdx.x * 4 + (tid >> 6);
    const int lane = tid & 63;
    const int b    = g / G;

    const float a0 = dA[g], a1 = dB[g], a2 = dC[g];
    const int   J0 = jA[g], J1 = jB[g], J2 = jC[g];

    const float W0 = 1.0f / fmaxf(a0, 1e-16f);
    const float W1 = 1.0f / fmaxf(a1, 1e-16f);
    const float W2 = 1.0f / fmaxf(a2, 1e-16f);

    const size_t rowBase = (size_t)b * M * 64;
    const float x0 = x[rowBase + (size_t)J0 * 64 + lane];
    const float x1 = x[rowBase + (size_t)J1 * 64 + lane];
    const float x2 = x[rowBase + (size_t)J2 * 64 + lane];

    const float num = ((W0 * x0) + (W1 * x1)) + (W2 * x2);   // unfused
    const float den = (W0 + W1) + W2;
    out[(size_t)g * 64 + lane] = num / den;
}

extern "C" void kernel_launch(void* const* d_in, const int* in_sizes, int n_in,
                              void* d_out, int out_size, void* d_ws, size_t ws_size,
                              hipStream_t stream) {
    const float* x        = (const float*)d_in[0];
    const float* mesh_pos = (const float*)d_in[1];
    const float* grid_pos = (const float*)d_in[2];
    // d_in[3] = batch_idx (int64) — contiguous repeat layout, unused.

    const int N  = in_sizes[1] / 2;   // 65536
    const int Gt = in_sizes[2] / 2;   // 16384
    const int B  = 8;
    const int M  = N / B;             // 8192
    const int G  = Gt / B;            // 2048

    // Workspace (~1.5 MB): starts + packed candidates + SoA results.
    char* p = (char*)d_ws;
    int*    starts = (int*)p;     p += (size_t)B * (NBINS + 1) * sizeof(int);
    float4* sxyi   = (float4*)p;  p += (size_t)N * sizeof(float4);
    float*  dA     = (float*)p;   p += (size_t)Gt * sizeof(float);
    float*  dB     = (float*)p;   p += (size_t)Gt * sizeof(float);
    float*  dC     = (float*)p;   p += (size_t)Gt * sizeof(float);
    int*    jA     = (int*)p;     p += (size_t)Gt * sizeof(int);
    int*    jB     = (int*)p;     p += (size_t)Gt * sizeof(int);
    int*    jC     = (int*)p;

    const size_t dsmBytes = (size_t)M * 12;   // 96 KB staged sort
    bin_all   <<<B, NTB, dsmBytes, stream>>>(mesh_pos, starts, sxyi, M);
    knn_select<<<Gt / PPB, BLK, 0, stream>>>(grid_pos, sxyi, starts,
                                             dA, dB, dC, jA, jB, jC, M, G);
    knn_gather<<<Gt / 4, BLK, 0, stream>>>(x, dA, dB, dC, jA, jB, jC,
                                           (float*)d_out, M, G);
}

// Round 18
// 21.810 us; speedup vs baseline: 1.2559x; 1.2559x over previous
//
#include <hip/hip_runtime.h>

// CfdInterpolateMeshToGrid: B=8, M=8192 mesh pts/batch, G=2048 grid pts/batch,
// D=2, C=64, K=3.  out[g,c] = sum_k w_k * x[nn_k(g), c] / sum_k w_k,
// w_k = 1 / max(d2_k, 1e-16), d2 = (g2 + m2) - 2*dot.
//
// NUMERICS (locked by rounds 1-5 — DO NOT CHANGE):
//   #pragma clang fp contract(off), plus exactly:
//     m2  = (mx*mx) + (my*my)           // unfused
//     g2  = (gx*gx) + (gy*gy)           // unfused
//     p0  = gx*mx; dot = fmaf(gy,my,p0) // fma-ascending k-contraction (BLAS)
//     t   = g2 + m2
//     d2  = fmaf(-2, dot, t)            // == t - (2*dot) bit-exactly
//   Selection = 3 lex-smallest (d2, idx) — identical to stable top_k and
//   visit-order independent (safe with nondeterministic scatter order).
//
// SCHEDULE (round 18): r17 (select/gather split) regressed — fused gather
// overlaps with other waves' scan; split serializes. Revert to r16 and fix
// its TLP ceiling: r16 ran 2048 waves = 2/SIMD (proven latency-starved,
// r9=48% busy vs r6's 4/SIMD=88%). Now LPG=16 -> 4096 waves = 4/SIMD, with
// the ring FLATTENED to one T-length list (2-compare segment decode/iter):
// lane utilization 90% (r15's per-row 16-lane scan was 75% — that + missing
// r16 improvements caused its regression). Merge = 4 shuffle levels; gather
// fused, 4 points/wave. bin_all unchanged from r16.

#define BLK 256
#define LPG 16           // lanes per grid point
#define PPB 16           // grid points per search block (BLK/LPG)
#define NTB 1024
#define NB 32
#define NBINS (NB * NB)
#define PADIDX 0x7FFFFFFF
#define MARGIN 1e-4f

// One block per batch: zero + histogram + scan + LDS-staged scatter +
// coalesced write-out of packed candidates (x, y, m2, idx_bits).
__global__ void bin_all(const float* __restrict__ mesh_pos,
                        int* __restrict__ starts,    // [B][NBINS+1]
                        float4* __restrict__ sxyi,
                        int M)
{
#pragma clang fp contract(off)
    __shared__ int h[NBINS];          // histogram, then cursor
    __shared__ int wsum[16];
    __shared__ int woff[17];
    extern __shared__ char dsm[];     // M*12 bytes: staged sorted array
    float2* stage = (float2*)dsm;
    int*    sidl  = (int*)(dsm + (size_t)M * sizeof(float2));

    const int b = blockIdx.x, t = threadIdx.x;

    h[t] = 0;                         // NBINS == NTB == 1024
    __syncthreads();

    const float2* mp = (const float2*)mesh_pos + (size_t)b * M;
    for (int n = t; n < M; n += NTB) {
        const float2 p = mp[n];
        const int bx = max(0, min((int)(p.x * (float)NB), NB - 1));
        const int by = max(0, min((int)(p.y * (float)NB), NB - 1));
        atomicAdd(&h[by * NB + bx], 1);
    }
    __syncthreads();

    const int v = h[t];
    int sc = v;                       // wave-inclusive scan
    #pragma unroll
    for (int off = 1; off < 64; off <<= 1) {
        int nv = __shfl_up(sc, off, 64);
        if ((t & 63) >= off) sc += nv;
    }
    if ((t & 63) == 63) wsum[t >> 6] = sc;
    __syncthreads();
    if (t == 0) {
        int acc = 0;
        #pragma unroll
        for (int i = 0; i < 16; ++i) { woff[i] = acc; acc += wsum[i]; }
        woff[16] = acc;
    }
    __syncthreads();
    const int excl = woff[t >> 6] + sc - v;
    starts[b * (NBINS + 1) + t] = excl;
    if (t == 0) starts[b * (NBINS + 1) + NBINS] = woff[16];   // = M
    __syncthreads();                  // everyone done reading h[t]
    h[t] = excl;                      // cursor
    __syncthreads();

    for (int n = t; n < M; n += NTB) {
        const float2 p = mp[n];       // L1 hit (just streamed)
        const int bx = max(0, min((int)(p.x * (float)NB), NB - 1));
        const int by = max(0, min((int)(p.y * (float)NB), NB - 1));
        const int pos = atomicAdd(&h[by * NB + bx], 1);
        stage[pos] = p;               // LDS scatter (cheap)
        sidl[pos]  = n;               // batch-local index
    }
    __syncthreads();

    // Coalesced write-out; m2 recomputed with the locked unfused expression.
    for (int n = t; n < M; n += NTB) {
        const float2 p = stage[n];
        const float m2 = (p.x * p.x) + (p.y * p.y);   // unfused (contract off)
        sxyi[(size_t)b * M + n] =
            make_float4(p.x, p.y, m2, __int_as_float(sidl[n]));
    }
}

// lex-(d2, idx) sorted-3 insert; visit-order independent == stable top_k.
#define LEX_INSERT(d2, idx)                                                  \
    if ((d2) < t2 || ((d2) == t2 && (idx) < i2)) {                           \
        if ((d2) < t1 || ((d2) == t1 && (idx) < i1)) {                       \
            t2 = t1; i2 = i1;                                                \
            if ((d2) < t0 || ((d2) == t0 && (idx) < i0)) {                   \
                t1 = t0; i1 = i0; t0 = (d2); i0 = (idx);                     \
            } else { t1 = (d2); i1 = (idx); }                                \
        } else { t2 = (d2); i2 = (idx); }                                    \
    }

// Search: block = 16 grid points, 16 lanes each; 1024 blocks (4 waves/SIMD).
// Flat ring scan, register merge, fused gather. No LDS, no barriers.
__global__ void knn_search(const float* __restrict__ x,
                           const float* __restrict__ grid_pos,
                           const float4* __restrict__ sxyi,
                           const int* __restrict__ starts,
                           float* __restrict__ out,
                           int M, int G)
{
#pragma clang fp contract(off)
    const int tid  = threadIdx.x;
    const int g0   = blockIdx.x * PPB;
    const int b    = g0 / G;              // uniform: PPB divides G
    const int pt   = tid >> 4;            // block-local point 0..15
    const int li   = tid & (LPG - 1);     // lane within point group
    const int lane = tid & 63;

    const int g = g0 + pt;
    const float2 gp = ((const float2*)grid_pos)[g];   // broadcast in group
    const float gx = gp.x, gy = gp.y;
    const float g2 = (gx * gx) + (gy * gy);           // unfused

    const int gbx = max(0, min((int)(gx * (float)NB), NB - 1));
    const int gby = max(0, min((int)(gy * (float)NB), NB - 1));
    const int bxlo = max(gbx - 1, 0), bxhi = min(gbx + 1, NB - 1);
    const int bylo = max(gby - 1, 0), byhi = min(gby + 1, NB - 1);

    const int* st = starts + b * (NBINS + 1);          // L2-resident (4KB)
    const float4* bxyi = sxyi + (size_t)b * M;

    // Hoist all row bounds (up to 6 loads issued before scanning).
    const int lo0 = st[bylo * NB + bxlo];
    const int hi0 = st[bylo * NB + bxhi + 1];
    int lo1 = 0, hi1 = 0, lo2 = 0, hi2 = 0;
    if (bylo + 1 <= byhi) { lo1 = st[(bylo + 1) * NB + bxlo];
                            hi1 = st[(bylo + 1) * NB + bxhi + 1]; }
    if (bylo + 2 <= byhi) { lo2 = st[(bylo + 2) * NB + bxlo];
                            hi2 = st[(bylo + 2) * NB + bxhi + 1]; }

    // Flatten the 3 segments into one T-length list (90% lane utilization
    // at LPG=16; segment decode = 2 compares).
    const int c0  = hi0 - lo0;
    const int c01 = c0 + (hi1 - lo1);
    const int T   = c01 + (hi2 - lo2);

    float t0 = 1e30f, t1 = 1e30f, t2 = 1e30f;
    int   i0 = PADIDX, i1 = PADIDX, i2 = PADIDX;

    for (int L = li; L < T; L += LPG) {
        int sp;
        if (L < c0)       sp = lo0 + L;
        else if (L < c01) sp = lo1 + (L - c0);
        else              sp = lo2 + (L - c01);
        const float4 v = bxyi[sp];
        const float p0  = gx * v.x;
        const float dot = fmaf(gy, v.y, p0);
        const float t   = g2 + v.z;                    // v.z = m2 (bit-exact)
        const float d2  = fmaf(-2.0f, dot, t);
        const int   idx = __float_as_int(v.w);
        LEX_INSERT(d2, idx)
    }

    // 16-lane lex extract-pop x3 -> registers (group-uniform after butterfly).
    float wd0, wd1, wd2; int wi0, wi1, wi2;
    #pragma unroll
    for (int r = 0; r < 3; ++r) {
        float rd = t0; int ri = i0;
        #pragma unroll
        for (int off = 1; off < LPG; off <<= 1) {
            float od = __shfl_xor(rd, off, 64);
            int   oi = __shfl_xor(ri, off, 64);
            if (od < rd || (od == rd && oi < ri)) { rd = od; ri = oi; }
        }
        if (r == 0)      { wd0 = rd; wi0 = ri; }
        else if (r == 1) { wd1 = rd; wi1 = ri; }
        else             { wd2 = rd; wi2 = ri; }
        if (t0 == rd && i0 == ri) {
            t0 = t1; i0 = i1; t1 = t2; i1 = i2; t2 = 1e30f; i2 = PADIDX;
        }
    }

    // Containment check (group-uniform): distance to unexamined region.
    const float w = 1.0f / (float)NB;
    const float dl = (bxlo > 0)      ? (gx - (float)bxlo * w)       : 1e30f;
    const float dr = (bxhi < NB - 1) ? ((float)(bxhi + 1) * w - gx) : 1e30f;
    const float dn = (bylo > 0)      ? (gy - (float)bylo * w)       : 1e30f;
    const float dt = (byhi < NB - 1) ? ((float)(byhi + 1) * w - gy) : 1e30f;
    const float bdd = fminf(fminf(dl, dr), fminf(dn, dt));
    const float bd2 = bdd * bdd;
    const bool need = (li == 0) && !(wd2 + MARGIN < bd2);

    // Rare fallback: wave-cooperative exact scan; deliver via registers.
    unsigned long long mask = __ballot(need);
    while (mask) {
        const int l = __builtin_ctzll(mask); mask &= mask - 1;
        const int ptf = ((tid & ~63) + l) >> 4;        // block-local point
        const float2 fgp = ((const float2*)grid_pos)[g0 + ptf];
        const float fgx = fgp.x, fgy = fgp.y;
        const float fg2 = (fgx * fgx) + (fgy * fgy);   // unfused
        float t0 = 1e30f, t1 = 1e30f, t2 = 1e30f;
        int   i0 = PADIDX, i1 = PADIDX, i2 = PADIDX;
        for (int j = lane; j < M; j += 64) {
            const float4 v = bxyi[j];
            const float p0  = fgx * v.x;
            const float dot = fmaf(fgy, v.y, p0);
            const float t   = fg2 + v.z;
            const float d2  = fmaf(-2.0f, dot, t);
            const int   idx = __float_as_int(v.w);
            LEX_INSERT(d2, idx)
        }
        #pragma unroll
        for (int r = 0; r < 3; ++r) {                  // 64-lane butterfly
            float rd = t0; int ri = i0;
            #pragma unroll
            for (int off = 32; off; off >>= 1) {
                float od = __shfl_xor(rd, off, 64);
                int   oi = __shfl_xor(ri, off, 64);
                if (od < rd || (od == rd && oi < ri)) { rd = od; ri = oi; }
            }
            if (pt == ptf) {                           // owning group only
                if (r == 0)      { wd0 = rd; wi0 = ri; }
                else if (r == 1) { wd1 = rd; wi1 = ri; }
                else             { wd2 = rd; wi2 = ri; }
            }
            if (t0 == rd && i0 == ri) {
                t0 = t1; i0 = i1; t1 = t2; i1 = i2; t2 = 1e30f; i2 = PADIDX;
            }
        }
    }

    // Gather: wave handles its own 4 points; results via shuffle broadcast.
    const int wv = tid >> 6;
    const size_t rowBase = (size_t)b * M * 64;
    #pragma unroll
    for (int q = 0; q < 4; ++q) {
        const int src = q << 4;                        // lane q*16 of this wave
        const float a0 = __shfl(wd0, src, 64);
        const float a1 = __shfl(wd1, src, 64);
        const float a2 = __shfl(wd2, src, 64);
        const int   J0 = __shfl(wi0, src, 64);
        const int   J1 = __shfl(wi1, src, 64);
        const int   J2 = __shfl(wi2, src, 64);
        const float W0 = 1.0f / fmaxf(a0, 1e-16f);
        const float W1 = 1.0f / fmaxf(a1, 1e-16f);
        const float W2 = 1.0f / fmaxf(a2, 1e-16f);
        const float x0 = x[rowBase + (size_t)J0 * 64 + lane];
        const float x1 = x[rowBase + (size_t)J1 * 64 + lane];
        const float x2 = x[rowBase + (size_t)J2 * 64 + lane];
        const float num = ((W0 * x0) + (W1 * x1)) + (W2 * x2);  // unfused
        const float den = (W0 + W1) + W2;
        out[(size_t)(g0 + (wv << 2) + q) * 64 + lane] = num / den;
    }
}

extern "C" void kernel_launch(void* const* d_in, const int* in_sizes, int n_in,
                              void* d_out, int out_size, void* d_ws, size_t ws_size,
                              hipStream_t stream) {
    const float* x        = (const float*)d_in[0];
    const float* mesh_pos = (const float*)d_in[1];
    const float* grid_pos = (const float*)d_in[2];
    // d_in[3] = batch_idx (int64) — contiguous repeat layout, unused.

    const int N  = in_sizes[1] / 2;   // 65536
    const int Gt = in_sizes[2] / 2;   // 16384
    const int B  = 8;
    const int M  = N / B;             // 8192
    const int G  = Gt / B;            // 2048

    // Workspace (~1.1 MB): starts + packed candidates.
    char* p = (char*)d_ws;
    int*    starts = (int*)p;     p += (size_t)B * (NBINS + 1) * sizeof(int);
    float4* sxyi   = (float4*)p;

    const size_t dsmBytes = (size_t)M * 12;   // 96 KB staged sort
    bin_all   <<<B, NTB, dsmBytes, stream>>>(mesh_pos, starts, sxyi, M);
    knn_search<<<Gt / PPB, BLK, 0, stream>>>(x, grid_pos, sxyi, starts,
                                             (float*)d_out, M, G);
}

// Round 19
// 21.694 us; speedup vs baseline: 1.2626x; 1.0053x over previous
//
#include <hip/hip_runtime.h>

// CfdInterpolateMeshToGrid: B=8, M=8192 mesh pts/batch, G=2048 grid pts/batch,
// D=2, C=64, K=3.  out[g,c] = sum_k w_k * x[nn_k(g), c] / sum_k w_k,
// w_k = 1 / max(d2_k, 1e-16), d2 = (g2 + m2) - 2*dot.
//
// NUMERICS (locked by rounds 1-5 — DO NOT CHANGE):
//   #pragma clang fp contract(off), plus exactly:
//     m2  = (mx*mx) + (my*my)           // unfused
//     g2  = (gx*gx) + (gy*gy)           // unfused
//     p0  = gx*mx; dot = fmaf(gy,my,p0) // fma-ascending k-contraction (BLAS)
//     t   = g2 + m2
//     d2  = fmaf(-2, dot, t)            // == t - (2*dot) bit-exactly
//   Selection = 3 lex-smallest (d2, idx) — identical to stable top_k and
//   visit-order independent (safe with nondeterministic scatter order).
//
// SCHEDULE (round 19): the TLP ladder is the operative lever (LPG=8: 24.7us
// -> LPG=16: 21.8us; search is latency-bound on scattered L2 ring loads +
// serial shuffle merge, not issue-bound). One more doubling: LPG=32, PPB=8,
// 2048 blocks = 8192 waves = 8/SIMD (full occupancy). Scan iterations 5->3,
// lane util 90%->75% (acceptable: +20% issue work vs 2x TLP), merge +1
// shuffle level, gather 2 points/wave. bin_all and all numerics unchanged.
// Pre-commit: if >=21.5us, TLP is exhausted -> next lever is grid-point
// binning for LDS ring sharing.

#define BLK 256
#define LPG 32           // lanes per grid point
#define PPB 8            // grid points per search block (BLK/LPG)
#define NTB 1024
#define NB 32
#define NBINS (NB * NB)
#define PADIDX 0x7FFFFFFF
#define MARGIN 1e-4f

// One block per batch: zero + histogram + scan + LDS-staged scatter +
// coalesced write-out of packed candidates (x, y, m2, idx_bits).
__global__ void bin_all(const float* __restrict__ mesh_pos,
                        int* __restrict__ starts,    // [B][NBINS+1]
                        float4* __restrict__ sxyi,
                        int M)
{
#pragma clang fp contract(off)
    __shared__ int h[NBINS];          // histogram, then cursor
    __shared__ int wsum[16];
    __shared__ int woff[17];
    extern __shared__ char dsm[];     // M*12 bytes: staged sorted array
    float2* stage = (float2*)dsm;
    int*    sidl  = (int*)(dsm + (size_t)M * sizeof(float2));

    const int b = blockIdx.x, t = threadIdx.x;

    h[t] = 0;                         // NBINS == NTB == 1024
    __syncthreads();

    const float2* mp = (const float2*)mesh_pos + (size_t)b * M;
    for (int n = t; n < M; n += NTB) {
        const float2 p = mp[n];
        const int bx = max(0, min((int)(p.x * (float)NB), NB - 1));
        const int by = max(0, min((int)(p.y * (float)NB), NB - 1));
        atomicAdd(&h[by * NB + bx], 1);
    }
    __syncthreads();

    const int v = h[t];
    int sc = v;                       // wave-inclusive scan
    #pragma unroll
    for (int off = 1; off < 64; off <<= 1) {
        int nv = __shfl_up(sc, off, 64);
        if ((t & 63) >= off) sc += nv;
    }
    if ((t & 63) == 63) wsum[t >> 6] = sc;
    __syncthreads();
    if (t == 0) {
        int acc = 0;
        #pragma unroll
        for (int i = 0; i < 16; ++i) { woff[i] = acc; acc += wsum[i]; }
        woff[16] = acc;
    }
    __syncthreads();
    const int excl = woff[t >> 6] + sc - v;
    starts[b * (NBINS + 1) + t] = excl;
    if (t == 0) starts[b * (NBINS + 1) + NBINS] = woff[16];   // = M
    __syncthreads();                  // everyone done reading h[t]
    h[t] = excl;                      // cursor
    __syncthreads();

    for (int n = t; n < M; n += NTB) {
        const float2 p = mp[n];       // L1 hit (just streamed)
        const int bx = max(0, min((int)(p.x * (float)NB), NB - 1));
        const int by = max(0, min((int)(p.y * (float)NB), NB - 1));
        const int pos = atomicAdd(&h[by * NB + bx], 1);
        stage[pos] = p;               // LDS scatter (cheap)
        sidl[pos]  = n;               // batch-local index
    }
    __syncthreads();

    // Coalesced write-out; m2 recomputed with the locked unfused expression.
    for (int n = t; n < M; n += NTB) {
        const float2 p = stage[n];
        const float m2 = (p.x * p.x) + (p.y * p.y);   // unfused (contract off)
        sxyi[(size_t)b * M + n] =
            make_float4(p.x, p.y, m2, __int_as_float(sidl[n]));
    }
}

// lex-(d2, idx) sorted-3 insert; visit-order independent == stable top_k.
#define LEX_INSERT(d2, idx)                                                  \
    if ((d2) < t2 || ((d2) == t2 && (idx) < i2)) {                           \
        if ((d2) < t1 || ((d2) == t1 && (idx) < i1)) {                       \
            t2 = t1; i2 = i1;                                                \
            if ((d2) < t0 || ((d2) == t0 && (idx) < i0)) {                   \
                t1 = t0; i1 = i0; t0 = (d2); i0 = (idx);                     \
            } else { t1 = (d2); i1 = (idx); }                                \
        } else { t2 = (d2); i2 = (idx); }                                    \
    }

// Search: block = 8 grid points, 32 lanes each; 2048 blocks (8 waves/SIMD).
// Flat ring scan, register merge, fused gather. No LDS, no barriers.
__global__ void knn_search(const float* __restrict__ x,
                           const float* __restrict__ grid_pos,
                           const float4* __restrict__ sxyi,
                           const int* __restrict__ starts,
                           float* __restrict__ out,
                           int M, int G)
{
#pragma clang fp contract(off)
    const int tid  = threadIdx.x;
    const int g0   = blockIdx.x * PPB;
    const int b    = g0 / G;              // uniform: PPB divides G
    const int pt   = tid >> 5;            // block-local point 0..7
    const int li   = tid & (LPG - 1);     // lane within point group
    const int lane = tid & 63;

    const int g = g0 + pt;
    const float2 gp = ((const float2*)grid_pos)[g];   // broadcast in group
    const float gx = gp.x, gy = gp.y;
    const float g2 = (gx * gx) + (gy * gy);           // unfused

    const int gbx = max(0, min((int)(gx * (float)NB), NB - 1));
    const int gby = max(0, min((int)(gy * (float)NB), NB - 1));
    const int bxlo = max(gbx - 1, 0), bxhi = min(gbx + 1, NB - 1);
    const int bylo = max(gby - 1, 0), byhi = min(gby + 1, NB - 1);

    const int* st = starts + b * (NBINS + 1);          // L2-resident (4KB)
    const float4* bxyi = sxyi + (size_t)b * M;

    // Hoist all row bounds (up to 6 loads issued before scanning).
    const int lo0 = st[bylo * NB + bxlo];
    const int hi0 = st[bylo * NB + bxhi + 1];
    int lo1 = 0, hi1 = 0, lo2 = 0, hi2 = 0;
    if (bylo + 1 <= byhi) { lo1 = st[(bylo + 1) * NB + bxlo];
                            hi1 = st[(bylo + 1) * NB + bxhi + 1]; }
    if (bylo + 2 <= byhi) { lo2 = st[(bylo + 2) * NB + bxlo];
                            hi2 = st[(bylo + 2) * NB + bxhi + 1]; }

    // Flatten the 3 segments into one T-length list.
    const int c0  = hi0 - lo0;
    const int c01 = c0 + (hi1 - lo1);
    const int T   = c01 + (hi2 - lo2);

    float t0 = 1e30f, t1 = 1e30f, t2 = 1e30f;
    int   i0 = PADIDX, i1 = PADIDX, i2 = PADIDX;

    for (int L = li; L < T; L += LPG) {
        int sp;
        if (L < c0)       sp = lo0 + L;
        else if (L < c01) sp = lo1 + (L - c0);
        else              sp = lo2 + (L - c01);
        const float4 v = bxyi[sp];
        const float p0  = gx * v.x;
        const float dot = fmaf(gy, v.y, p0);
        const float t   = g2 + v.z;                    // v.z = m2 (bit-exact)
        const float d2  = fmaf(-2.0f, dot, t);
        const int   idx = __float_as_int(v.w);
        LEX_INSERT(d2, idx)
    }

    // 32-lane lex extract-pop x3 -> registers (group-uniform after butterfly).
    float wd0, wd1, wd2; int wi0, wi1, wi2;
    #pragma unroll
    for (int r = 0; r < 3; ++r) {
        float rd = t0; int ri = i0;
        #pragma unroll
        for (int off = 1; off < LPG; off <<= 1) {
            float od = __shfl_xor(rd, off, 64);
            int   oi = __shfl_xor(ri, off, 64);
            if (od < rd || (od == rd && oi < ri)) { rd = od; ri = oi; }
        }
        if (r == 0)      { wd0 = rd; wi0 = ri; }
        else if (r == 1) { wd1 = rd; wi1 = ri; }
        else             { wd2 = rd; wi2 = ri; }
        if (t0 == rd && i0 == ri) {
            t0 = t1; i0 = i1; t1 = t2; i1 = i2; t2 = 1e30f; i2 = PADIDX;
        }
    }

    // Containment check (group-uniform): distance to unexamined region.
    const float w = 1.0f / (float)NB;
    const float dl = (bxlo > 0)      ? (gx - (float)bxlo * w)       : 1e30f;
    const float dr = (bxhi < NB - 1) ? ((float)(bxhi + 1) * w - gx) : 1e30f;
    const float dn = (bylo > 0)      ? (gy - (float)bylo * w)       : 1e30f;
    const float dt = (byhi < NB - 1) ? ((float)(byhi + 1) * w - gy) : 1e30f;
    const float bdd = fminf(fminf(dl, dr), fminf(dn, dt));
    const float bd2 = bdd * bdd;
    const bool need = (li == 0) && !(wd2 + MARGIN < bd2);

    // Rare fallback: wave-cooperative exact scan; deliver via registers.
    unsigned long long mask = __ballot(need);
    while (mask) {
        const int l = __builtin_ctzll(mask); mask &= mask - 1;
        const int ptf = ((tid & ~63) + l) >> 5;        // block-local point
        const float2 fgp = ((const float2*)grid_pos)[g0 + ptf];
        const float fgx = fgp.x, fgy = fgp.y;
        const float fg2 = (fgx * fgx) + (fgy * fgy);   // unfused
        float t0 = 1e30f, t1 = 1e30f, t2 = 1e30f;
        int   i0 = PADIDX, i1 = PADIDX, i2 = PADIDX;
        for (int j = lane; j < M; j += 64) {
            const float4 v = bxyi[j];
            const float p0  = fgx * v.x;
            const float dot = fmaf(fgy, v.y, p0);
            const float t   = fg2 + v.z;
            const float d2  = fmaf(-2.0f, dot, t);
            const int   idx = __float_as_int(v.w);
            LEX_INSERT(d2, idx)
        }
        #pragma unroll
        for (int r = 0; r < 3; ++r) {                  // 64-lane butterfly
            float rd = t0; int ri = i0;
            #pragma unroll
            for (int off = 32; off; off >>= 1) {
                float od = __shfl_xor(rd, off, 64);
                int   oi = __shfl_xor(ri, off, 64);
                if (od < rd || (od == rd && oi < ri)) { rd = od; ri = oi; }
            }
            if (pt == ptf) {                           // owning group only
                if (r == 0)      { wd0 = rd; wi0 = ri; }
                else if (r == 1) { wd1 = rd; wi1 = ri; }
                else             { wd2 = rd; wi2 = ri; }
            }
            if (t0 == rd && i0 == ri) {
                t0 = t1; i0 = i1; t1 = t2; i1 = i2; t2 = 1e30f; i2 = PADIDX;
            }
        }
    }

    // Gather: wave handles its own 2 points; results via shuffle broadcast.
    const int wv = tid >> 6;
    const size_t rowBase = (size_t)b * M * 64;
    #pragma unroll
    for (int q = 0; q < 2; ++q) {
        const int src = q << 5;                        // lane q*32 of this wave
        const float a0 = __shfl(wd0, src, 64);
        const float a1 = __shfl(wd1, src, 64);
        const float a2 = __shfl(wd2, src, 64);
        const int   J0 = __shfl(wi0, src, 64);
        const int   J1 = __shfl(wi1, src, 64);
        const int   J2 = __shfl(wi2, src, 64);
        const float W0 = 1.0f / fmaxf(a0, 1e-16f);
        const float W1 = 1.0f / fmaxf(a1, 1e-16f);
        const float W2 = 1.0f / fmaxf(a2, 1e-16f);
        const float x0 = x[rowBase + (size_t)J0 * 64 + lane];
        const float x1 = x[rowBase + (size_t)J1 * 64 + lane];
        const float x2 = x[rowBase + (size_t)J2 * 64 + lane];
        const float num = ((W0 * x0) + (W1 * x1)) + (W2 * x2);  // unfused
        const float den = (W0 + W1) + W2;
        out[(size_t)(g0 + (wv << 1) + q) * 64 + lane] = num / den;
    }
}

extern "C" void kernel_launch(void* const* d_in, const int* in_sizes, int n_in,
                              void* d_out, int out_size, void* d_ws, size_t ws_size,
                              hipStream_t stream) {
    const float* x        = (const float*)d_in[0];
    const float* mesh_pos = (const float*)d_in[1];
    const float* grid_pos = (const float*)d_in[2];
    // d_in[3] = batch_idx (int64) — contiguous repeat layout, unused.

    const int N  = in_sizes[1] / 2;   // 65536
    const int Gt = in_sizes[2] / 2;   // 16384
    const int B  = 8;
    const int M  = N / B;             // 8192
    const int G  = Gt / B;            // 2048

    // Workspace (~1.1 MB): starts + packed candidates.
    char* p = (char*)d_ws;
    int*    starts = (int*)p;     p += (size_t)B * (NBINS + 1) * sizeof(int);
    float4* sxyi   = (float4*)p;

    const size_t dsmBytes = (size_t)M * 12;   // 96 KB staged sort
    bin_all   <<<B, NTB, dsmBytes, stream>>>(mesh_pos, starts, sxyi, M);
    knn_search<<<Gt / PPB, BLK, 0, stream>>>(x, grid_pos, sxyi, starts,
                                             (float*)d_out, M, G);
}

// Round 20
// 19.590 us; speedup vs baseline: 1.3982x; 1.1074x over previous
//
#include <hip/hip_runtime.h>

// CfdInterpolateMeshToGrid: B=8, M=8192 mesh pts/batch, G=2048 grid pts/batch,
// D=2, C=64, K=3.  out[g,c] = sum_k w_k * x[nn_k(g), c] / sum_k w_k,
// w_k = 1 / max(d2_k, 1e-16), d2 = (g2 + m2) - 2*dot.
//
// NUMERICS (locked by rounds 1-5 — DO NOT CHANGE):
//   #pragma clang fp contract(off), plus exactly:
//     m2  = (mx*mx) + (my*my)           // unfused
//     g2  = (gx*gx) + (gy*gy)           // unfused
//     p0  = gx*mx; dot = fmaf(gy,my,p0) // fma-ascending k-contraction (BLAS)
//     t   = g2 + m2
//     d2  = fmaf(-2, dot, t)            // == t - (2*dot) bit-exactly
//   Selection = 3 lex-smallest (d2, idx) — identical to stable top_k and
//   visit-order independent.
//
// SCHEDULE (round 20): r19 proved TLP is saturated (LPG=16->32 flat). Two
// latency/locality fixes, selection-preserving:
//  (a) MERGE NETWORK: replace 3x(5-level butterfly + pop) [15 serial
//      cross-lane steps] with ONE 5-level sorted-3 merge butterfly:
//      per level, merge my sorted-3 with partner's sorted-3 keeping the
//      lex-3-smallest (r0=min(a0,b0); r1=min(max(a0,b0),min(a1,b1));
//      r2=min(max(of r1 losers), min(a2,b2))) — exact merge identity.
//      Result is group-uniform on ALL lanes (no leader, no pops).
//  (b) XCD-BATCH AFFINITY (T1): per-batch x-slab (2MB) + candidates (128KB)
//      fit one XCD's 4MB L2, but round-robin dispatch thrashes all 8 L2s
//      with the 16MB working set. Swizzle logical = (bid>>3)+(bid&7)*256
//      (bijective, 2048=8x256) so batch c's 256 blocks land on XCD c ->
//      gather rows become L2-hits.

#define BLK 256
#define LPG 32           // lanes per grid point
#define PPB 8            // grid points per search block (BLK/LPG)
#define NTB 1024
#define NB 32
#define NBINS (NB * NB)
#define PADIDX 0x7FFFFFFF
#define MARGIN 1e-4f

// One block per batch: zero + histogram + scan + LDS-staged scatter +
// coalesced write-out of packed candidates (x, y, m2, idx_bits).
__global__ void bin_all(const float* __restrict__ mesh_pos,
                        int* __restrict__ starts,    // [B][NBINS+1]
                        float4* __restrict__ sxyi,
                        int M)
{
#pragma clang fp contract(off)
    __shared__ int h[NBINS];          // histogram, then cursor
    __shared__ int wsum[16];
    __shared__ int woff[17];
    extern __shared__ char dsm[];     // M*12 bytes: staged sorted array
    float2* stage = (float2*)dsm;
    int*    sidl  = (int*)(dsm + (size_t)M * sizeof(float2));

    const int b = blockIdx.x, t = threadIdx.x;

    h[t] = 0;                         // NBINS == NTB == 1024
    __syncthreads();

    const float2* mp = (const float2*)mesh_pos + (size_t)b * M;
    for (int n = t; n < M; n += NTB) {
        const float2 p = mp[n];
        const int bx = max(0, min((int)(p.x * (float)NB), NB - 1));
        const int by = max(0, min((int)(p.y * (float)NB), NB - 1));
        atomicAdd(&h[by * NB + bx], 1);
    }
    __syncthreads();

    const int v = h[t];
    int sc = v;                       // wave-inclusive scan
    #pragma unroll
    for (int off = 1; off < 64; off <<= 1) {
        int nv = __shfl_up(sc, off, 64);
        if ((t & 63) >= off) sc += nv;
    }
    if ((t & 63) == 63) wsum[t >> 6] = sc;
    __syncthreads();
    if (t == 0) {
        int acc = 0;
        #pragma unroll
        for (int i = 0; i < 16; ++i) { woff[i] = acc; acc += wsum[i]; }
        woff[16] = acc;
    }
    __syncthreads();
    const int excl = woff[t >> 6] + sc - v;
    starts[b * (NBINS + 1) + t] = excl;
    if (t == 0) starts[b * (NBINS + 1) + NBINS] = woff[16];   // = M
    __syncthreads();                  // everyone done reading h[t]
    h[t] = excl;                      // cursor
    __syncthreads();

    for (int n = t; n < M; n += NTB) {
        const float2 p = mp[n];       // L1 hit (just streamed)
        const int bx = max(0, min((int)(p.x * (float)NB), NB - 1));
        const int by = max(0, min((int)(p.y * (float)NB), NB - 1));
        const int pos = atomicAdd(&h[by * NB + bx], 1);
        stage[pos] = p;               // LDS scatter (cheap)
        sidl[pos]  = n;               // batch-local index
    }
    __syncthreads();

    // Coalesced write-out; m2 recomputed with the locked unfused expression.
    for (int n = t; n < M; n += NTB) {
        const float2 p = stage[n];
        const float m2 = (p.x * p.x) + (p.y * p.y);   // unfused (contract off)
        sxyi[(size_t)b * M + n] =
            make_float4(p.x, p.y, m2, __int_as_float(sidl[n]));
    }
}

// lex-(d2, idx) sorted-3 insert; visit-order independent == stable top_k.
#define LEX_INSERT(d2, idx)                                                  \
    if ((d2) < t2 || ((d2) == t2 && (idx) < i2)) {                           \
        if ((d2) < t1 || ((d2) == t1 && (idx) < i1)) {                       \
            t2 = t1; i2 = i1;                                                \
            if ((d2) < t0 || ((d2) == t0 && (idx) < i0)) {                   \
                t1 = t0; i1 = i0; t0 = (d2); i0 = (idx);                     \
            } else { t1 = (d2); i1 = (idx); }                                \
        } else { t2 = (d2); i2 = (idx); }                                    \
    }

// One butterfly level of the sorted-3 merge network over 'span' lanes:
// exchange sorted-3 with XOR partner, keep lex-3-smallest of the union.
#define MERGE3_LEVEL(off)                                                    \
    {                                                                        \
        const float o0 = __shfl_xor(t0, (off), 64);                          \
        const int   p0_ = __shfl_xor(i0, (off), 64);                         \
        const float o1 = __shfl_xor(t1, (off), 64);                          \
        const int   p1_ = __shfl_xor(i1, (off), 64);                         \
        const float o2 = __shfl_xor(t2, (off), 64);                          \
        const int   p2_ = __shfl_xor(i2, (off), 64);                         \
        float c0d, d0d; int c0i, d0i;                                        \
        if (o0 < t0 || (o0 == t0 && p0_ < i0))                               \
             { c0d = o0; c0i = p0_; d0d = t0; d0i = i0; }                    \
        else { c0d = t0; c0i = i0; d0d = o0; d0i = p0_; }                    \
        float c1d; int c1i;                                                  \
        if (o1 < t1 || (o1 == t1 && p1_ < i1)) { c1d = o1; c1i = p1_; }      \
        else                                   { c1d = t1; c1i = i1; }      \
        float c2d; int c2i;                                                  \
        if (o2 < t2 || (o2 == t2 && p2_ < i2)) { c2d = o2; c2i = p2_; }      \
        else                                   { c2d = t2; c2i = i2; }      \
        float r1d, l1d; int r1i, l1i;                                        \
        if (c1d < d0d || (c1d == d0d && c1i < d0i))                          \
             { r1d = c1d; r1i = c1i; l1d = d0d; l1i = d0i; }                 \
        else { r1d = d0d; r1i = d0i; l1d = c1d; l1i = c1i; }                 \
        float r2d; int r2i;                                                  \
        if (c2d < l1d || (c2d == l1d && c2i < l1i)) { r2d = c2d; r2i = c2i; }\
        else                                        { r2d = l1d; r2i = l1i; }\
        t0 = c0d; i0 = c0i; t1 = r1d; i1 = r1i; t2 = r2d; i2 = r2i;          \
    }

// Search: block = 8 grid points, 32 lanes each; 2048 blocks, XCD-batch
// affinity swizzle. Flat ring scan, merge-network reduce, fused gather.
__global__ void knn_search(const float* __restrict__ x,
                           const float* __restrict__ grid_pos,
                           const float4* __restrict__ sxyi,
                           const int* __restrict__ starts,
                           float* __restrict__ out,
                           int M, int G)
{
#pragma clang fp contract(off)
    const int tid  = threadIdx.x;
    // XCD-batch affinity: batch c's 256 blocks all carry bid%8 == c.
    const int lb   = (blockIdx.x >> 3) + (blockIdx.x & 7) * 256;
    const int g0   = lb * PPB;
    const int b    = g0 / G;              // == blockIdx.x & 7
    const int pt   = tid >> 5;            // block-local point 0..7
    const int li   = tid & (LPG - 1);     // lane within point group
    const int lane = tid & 63;

    const int g = g0 + pt;
    const float2 gp = ((const float2*)grid_pos)[g];   // broadcast in group
    const float gx = gp.x, gy = gp.y;
    const float g2 = (gx * gx) + (gy * gy);           // unfused

    const int gbx = max(0, min((int)(gx * (float)NB), NB - 1));
    const int gby = max(0, min((int)(gy * (float)NB), NB - 1));
    const int bxlo = max(gbx - 1, 0), bxhi = min(gbx + 1, NB - 1);
    const int bylo = max(gby - 1, 0), byhi = min(gby + 1, NB - 1);

    const int* st = starts + b * (NBINS + 1);          // L2-resident (4KB)
    const float4* bxyi = sxyi + (size_t)b * M;

    // Hoist all row bounds (up to 6 loads issued before scanning).
    const int lo0 = st[bylo * NB + bxlo];
    const int hi0 = st[bylo * NB + bxhi + 1];
    int lo1 = 0, hi1 = 0, lo2 = 0, hi2 = 0;
    if (bylo + 1 <= byhi) { lo1 = st[(bylo + 1) * NB + bxlo];
                            hi1 = st[(bylo + 1) * NB + bxhi + 1]; }
    if (bylo + 2 <= byhi) { lo2 = st[(bylo + 2) * NB + bxlo];
                            hi2 = st[(bylo + 2) * NB + bxhi + 1]; }

    // Flatten the 3 segments into one T-length list.
    const int c0  = hi0 - lo0;
    const int c01 = c0 + (hi1 - lo1);
    const int T   = c01 + (hi2 - lo2);

    float t0 = 1e30f, t1 = 1e30f, t2 = 1e30f;
    int   i0 = PADIDX, i1 = PADIDX, i2 = PADIDX;

    for (int L = li; L < T; L += LPG) {
        int sp;
        if (L < c0)       sp = lo0 + L;
        else if (L < c01) sp = lo1 + (L - c0);
        else              sp = lo2 + (L - c01);
        const float4 v = bxyi[sp];
        const float p0  = gx * v.x;
        const float dot = fmaf(gy, v.y, p0);
        const float t   = g2 + v.z;                    // v.z = m2 (bit-exact)
        const float d2  = fmaf(-2.0f, dot, t);
        const int   idx = __float_as_int(v.w);
        LEX_INSERT(d2, idx)
    }

    // 5-level sorted-3 merge network within the 32-lane group: after this,
    // (t0,t1,t2)/(i0,i1,i2) = lex-top-3 of the group union, on ALL lanes.
    MERGE3_LEVEL(1)  MERGE3_LEVEL(2)  MERGE3_LEVEL(4)
    MERGE3_LEVEL(8)  MERGE3_LEVEL(16)
    float wd0 = t0, wd1 = t1, wd2 = t2;
    int   wi0 = i0, wi1 = i1, wi2 = i2;

    // Containment check (group-uniform): distance to unexamined region.
    const float w = 1.0f / (float)NB;
    const float dl = (bxlo > 0)      ? (gx - (float)bxlo * w)       : 1e30f;
    const float dr = (bxhi < NB - 1) ? ((float)(bxhi + 1) * w - gx) : 1e30f;
    const float dn = (bylo > 0)      ? (gy - (float)bylo * w)       : 1e30f;
    const float dt = (byhi < NB - 1) ? ((float)(byhi + 1) * w - gy) : 1e30f;
    const float bdd = fminf(fminf(dl, dr), fminf(dn, dt));
    const float bd2 = bdd * bdd;
    const bool need = (li == 0) && !(wd2 + MARGIN < bd2);

    // Rare fallback: wave-cooperative exact scan (merge network over 64).
    unsigned long long mask = __ballot(need);
    while (mask) {
        const int l = __builtin_ctzll(mask); mask &= mask - 1;
        const int ptf = ((tid & ~63) + l) >> 5;        // block-local point
        const float2 fgp = ((const float2*)grid_pos)[g0 + ptf];
        const float fgx = fgp.x, fgy = fgp.y;
        const float fg2 = (fgx * fgx) + (fgy * fgy);   // unfused
        t0 = 1e30f; t1 = 1e30f; t2 = 1e30f;
        i0 = PADIDX; i1 = PADIDX; i2 = PADIDX;
        for (int j = lane; j < M; j += 64) {
            const float4 v = bxyi[j];
            const float p0  = fgx * v.x;
            const float dot = fmaf(fgy, v.y, p0);
            const float t   = fg2 + v.z;
            const float d2  = fmaf(-2.0f, dot, t);
            const int   idx = __float_as_int(v.w);
            LEX_INSERT(d2, idx)
        }
        MERGE3_LEVEL(1)  MERGE3_LEVEL(2)  MERGE3_LEVEL(4)
        MERGE3_LEVEL(8)  MERGE3_LEVEL(16) MERGE3_LEVEL(32)
        if (pt == ptf) { wd0 = t0; wi0 = i0; wd1 = t1; wi1 = i1;
                         wd2 = t2; wi2 = i2; }
    }

    // Gather: wave handles its own 2 points; results via shuffle broadcast.
    const int wv = tid >> 6;
    const size_t rowBase = (size_t)b * M * 64;
    #pragma unroll
    for (int q = 0; q < 2; ++q) {
        const int src = q << 5;                        // lane q*32 of this wave
        const float a0 = __shfl(wd0, src, 64);
        const float a1 = __shfl(wd1, src, 64);
        const float a2 = __shfl(wd2, src, 64);
        const int   J0 = __shfl(wi0, src, 64);
        const int   J1 = __shfl(wi1, src, 64);
        const int   J2 = __shfl(wi2, src, 64);
        const float W0 = 1.0f / fmaxf(a0, 1e-16f);
        const float W1 = 1.0f / fmaxf(a1, 1e-16f);
        const float W2 = 1.0f / fmaxf(a2, 1e-16f);
        const float x0 = x[rowBase + (size_t)J0 * 64 + lane];
        const float x1 = x[rowBase + (size_t)J1 * 64 + lane];
        const float x2 = x[rowBase + (size_t)J2 * 64 + lane];
        const float num = ((W0 * x0) + (W1 * x1)) + (W2 * x2);  // unfused
        const float den = (W0 + W1) + W2;
        out[(size_t)(g0 + (wv << 1) + q) * 64 + lane] = num / den;
    }
}

extern "C" void kernel_launch(void* const* d_in, const int* in_sizes, int n_in,
                              void* d_out, int out_size, void* d_ws, size_t ws_size,
                              hipStream_t stream) {
    const float* x        = (const float*)d_in[0];
    const float* mesh_pos = (const float*)d_in[1];
    const float* grid_pos = (const float*)d_in[2];
    // d_in[3] = batch_idx (int64) — contiguous repeat layout, unused.

    const int N  = in_sizes[1] / 2;   // 65536
    const int Gt = in_sizes[2] / 2;   // 16384
    const int B  = 8;
    const int M  = N / B;             // 8192
    const int G  = Gt / B;            // 2048

    // Workspace (~1.1 MB): starts + packed candidates.
    char* p = (char*)d_ws;
    int*    starts = (int*)p;     p += (size_t)B * (NBINS + 1) * sizeof(int);
    float4* sxyi   = (float4*)p;

    const size_t dsmBytes = (size_t)M * 12;   // 96 KB staged sort
    bin_all   <<<B, NTB, dsmBytes, stream>>>(mesh_pos, starts, sxyi, M);
    knn_search<<<Gt / PPB, BLK, 0, stream>>>(x, grid_pos, sxyi, starts,
                                             (float*)d_out, M, G);
}